// Round 5
// baseline (1689.296 us; speedup 1.0000x reference)
//
#include <hip/hip_runtime.h>
#include <math.h>

#define TT 512
#define VV 32000
#define NB 250          // blocks; 250*128 = 32000 columns
#define NTHR 512        // 8 waves
#define BCOLS 128
#define MAXIT 1000
#define CHK 50
#define NCHK (MAXIT / CHK)
#define LDS_BYTES 136576

typedef float f4 __attribute__((ext_vector_type(4)));
typedef _Float16 h8 __attribute__((ext_vector_type(8)));
typedef _Float16 h2 __attribute__((ext_vector_type(2)));
typedef unsigned long long u64;

// ---- DPP wave reductions ----
template <int CTRL>
__device__ __forceinline__ float dpp_add(float x) {
  int y = __builtin_amdgcn_update_dpp(0, __builtin_bit_cast(int, x), CTRL, 0xF, 0xF, true);
  return x + __builtin_bit_cast(float, y);
}
__device__ __forceinline__ float red16(float x) {  // valid on lanes 15 mod 16
  x = dpp_add<0x111>(x); x = dpp_add<0x112>(x);
  x = dpp_add<0x114>(x); x = dpp_add<0x118>(x);
  return x;
}
__device__ __forceinline__ float red32(float x) {  // valid on lanes 31, 63
  x = red16(x); x = dpp_add<0x142>(x); return x;
}
__device__ __forceinline__ float red64(float x) {  // valid on lane 63
  x = red32(x); x = dpp_add<0x143>(x); return x;
}

__device__ __forceinline__ int fswz(int row) { return (row ^ (row >> 5)) & 15; }

__device__ __forceinline__ u64 ald(const u64* p) {
  return __hip_atomic_load(p, __ATOMIC_RELAXED, __HIP_MEMORY_SCOPE_AGENT);
}
__device__ __forceinline__ void ast(u64* p, u64 v) {
  __hip_atomic_store(p, v, __ATOMIC_RELAXED, __HIP_MEMORY_SCOPE_AGENT);
}
__device__ __forceinline__ float aldf(const float* p) {
  return __hip_atomic_load(p, __ATOMIC_RELAXED, __HIP_MEMORY_SCOPE_AGENT);
}

extern "C" __global__ void __launch_bounds__(NTHR, 1)
sink_kernel(const float* __restrict__ cost, u64* __restrict__ partial,
            u64* __restrict__ upair, float* __restrict__ errb,
            float* __restrict__ lossp) {
  extern __shared__ char smem[];
  h8*       tile8  = (h8*)smem;                      // 512 x 16 chunks (swizzled), 128 KB
  float*    uf     = (float*)(smem + 131072);        // 512 f32
  float*    u_prev = (float*)(smem + 133120);        // 512 f32
  float*    vf     = (float*)(smem + 135168);        // 128 f32
  float*    v_prev = (float*)(smem + 135680);        // 128 f32
  _Float16* vh     = (_Float16*)(smem + 136192);     // 128 f16
  h8*       vh8    = (h8*)vh;
  float*    errw   = (float*)(smem + 136448);        // 16 f32
  float*    wred   = (float*)(smem + 136512);        // 8 f32
  int*      jflag  = (int*)(smem + 136544);          // 8 i32 (row-pair flags)

  const int t  = threadIdx.x;
  const int b  = blockIdx.x;
  const int cB = t & 15;        // chunk (8 cols)   — row-wise map (Phase B)
  const int rB = t >> 4;        // row slice 0..31
  const int gA = t >> 5;        // col-chunk        — Phase A map
  const int sA = t & 31;        // row-within-chunk 0..31
  const int wv = t >> 6, ln = t & 63;

  const float* cb = cost + (size_t)b * BCOLS;

  // ---- load tile: K~ = fp16(exp(-20 c)) ----
  for (int i = 0; i < 16; ++i) {
    int row = rB + 32 * i;
    const float* p = cb + (size_t)row * VV + cB * 8;
    f4 x0 = *(const f4*)p;
    f4 x1 = *(const f4*)(p + 4);
    h8 kk;
#pragma unroll
    for (int e = 0; e < 4; ++e) kk[e]     = (_Float16)__expf(-20.f * x0[e]);
#pragma unroll
    for (int e = 0; e < 4; ++e) kk[4 + e] = (_Float16)__expf(-20.f * x1[e]);
    tile8[row * 16 + (cB ^ fswz(row))] = kk;
  }
  if (t < 8) jflag[t] = 0;
  __syncthreads();

  const int rlo = (b * TT) / NB, rhi = ((b + 1) * TT) / NB;  // owned rows
  const bool writerA = ((t & 31) == 31);
  bool converged = false;

  for (int it = 0; it < MAXIT; ++it) {
    const unsigned stU = (unsigned)(it + 1);   // u stamp consumed this iter (u_it)
    const u64 pstamp  = ((u64)(it + 1)) << 32; // partial stamp published this iter
    const u64 ustampP = ((u64)(it + 2)) << 32; // upair stamp published (u_{it+1})
    const bool chkc = (it > 0) && (it % CHK == 0);
    const bool pending = ((it % CHK) == 1) && (it > CHK);
    const int ciW = it / CHK - 1;
    const int ciR = (it - 1) / CHK - 1;

    if (pending) { u_prev[t] = uf[t]; __syncthreads(); }

    // ---- Phase A: acc_j = sum_rows K~ * u_bar, row-pair pipelined ----
    float acc[8];
#pragma unroll
    for (int e = 0; e < 8; ++e) acc[e] = 0.f;

    if (t < 64) {
      // whole wave 0: sole global poller. lane t polls rows 64j+t.
      // No spin depends on masked-off lanes of THIS wave (deadlock-safe).
#pragma unroll 1
      for (int j = 0; j < 8; ++j) {
        u64 pv;
        for (;;) {
          pv = ald(&upair[64 * j + t]);
          if (__all((unsigned)(pv >> 32) == stU)) break;
        }
        uf[64 * j + t] = __builtin_bit_cast(float, (unsigned)pv);
        asm volatile("s_waitcnt lgkmcnt(0)" ::: "memory");
        if (t == 0)
          __hip_atomic_store(&jflag[j], (int)stU, __ATOMIC_RELEASE,
                             __HIP_MEMORY_SCOPE_WORKGROUP);
        if (pending && j == 0) {
          if (aldf(&errb[ciR]) < 0.005f * VV) { converged = true; break; }
        }
#pragma unroll
        for (int ii = 0; ii < 2; ++ii) {
          int row = 64 * j + 32 * ii + sA;
          h8 kk = tile8[row * 16 + (gA ^ fswz(row))];
          float uu = uf[row];
#pragma unroll
          for (int e = 0; e < 8; ++e) acc[e] = fmaf((float)kk[e], uu, acc[e]);
        }
      }
    } else {
      // waves 1-7: spin on flags produced by wave 0 (cross-wave: safe)
#pragma unroll 1
      for (int j = 0; j < 8; ++j) {
        while (__hip_atomic_load(&jflag[j], __ATOMIC_ACQUIRE,
                                 __HIP_MEMORY_SCOPE_WORKGROUP) != (int)stU) {}
        if (pending && j == 0) {
          if (aldf(&errb[ciR]) < 0.005f * VV) { converged = true; break; }
        }
#pragma unroll
        for (int ii = 0; ii < 2; ++ii) {
          int row = 64 * j + 32 * ii + sA;
          h8 kk = tile8[row * 16 + (gA ^ fswz(row))];
          float uu = uf[row];
#pragma unroll
          for (int e = 0; e < 8; ++e) acc[e] = fmaf((float)kk[e], uu, acc[e]);
        }
      }
    }
    if (converged) break;  // uniform: errb final & identical across all blocks

#pragma unroll
    for (int e = 0; e < 8; ++e) acc[e] = red32(acc[e]);

    // ---- v_bar = 1/(Sa + 1e-16); err uses OLD v ----
    if (writerA) {
      float el = 0.f;
#pragma unroll
      for (int e = 0; e < 8; ++e) {
        float sa = acc[e] * (1.f / TT);
        float vo = vf[gA * 8 + e];
        if (chkc) { el += fabsf(vo * sa - 1.f); v_prev[gA * 8 + e] = vo; }
        float nv = 1.f / (sa + 1e-16f);
        vf[gA * 8 + e] = nv;
        vh[gA * 8 + e] = (_Float16)nv;
      }
      if (chkc) errw[gA] = el;
    }
    __syncthreads();
    if (chkc) {
      if (t == 0) {
        float s = 0.f;
#pragma unroll
        for (int w = 0; w < 16; ++w) s += errw[w];
        __hip_atomic_fetch_add(&errb[ciW], s, __ATOMIC_RELAXED, __HIP_MEMORY_SCOPE_AGENT);
      }
      __syncthreads();  // drain err add before any partial store of this iter
    }

    // ---- Phase B: row partials, stamped; owner poll interleaved at its chunk ----
    h8 vv = vh8[cB];
    const bool isowner = (wv < rhi - rlo);
    const int orow = rlo + wv;
    const int ochunk = orow >> 5;
#pragma unroll 1
    for (int i = 0; i < 16; ++i) {
      int row = rB + 32 * i;
      h8 kk = tile8[row * 16 + (cB ^ fswz(row))];
      float rs = 0.f;
      rs = __builtin_amdgcn_fdot2(h2{kk[0], kk[1]}, h2{vv[0], vv[1]}, rs, false);
      rs = __builtin_amdgcn_fdot2(h2{kk[2], kk[3]}, h2{vv[2], vv[3]}, rs, false);
      rs = __builtin_amdgcn_fdot2(h2{kk[4], kk[5]}, h2{vv[4], vv[5]}, rs, false);
      rs = __builtin_amdgcn_fdot2(h2{kk[6], kk[7]}, h2{vv[6], vv[7]}, rs, false);
      rs = red16(rs);
      if ((t & 15) == 15)
        ast(&partial[(size_t)b * TT + row], pstamp | (u64)__builtin_bit_cast(unsigned, rs));
      if (isowner && i == ochunk) {
        // whole-wave uniform poll of 250 blocks' partials for owned row
        float vals[4];
        for (;;) {
          bool done = true;
#pragma unroll
          for (int k = 0; k < 4; ++k) {
            int bb = ln + 64 * k;
            vals[k] = 0.f;
            if (bb < NB) {
              u64 pvv = ald(&partial[(size_t)bb * TT + orow]);
              done = done && ((unsigned)(pvv >> 32) == stU);
              vals[k] = __builtin_bit_cast(float, (unsigned)pvv);
            }
          }
          if (__all(done)) break;
        }
        float s = vals[0] + vals[1] + vals[2] + vals[3];
        s = red64(s);
        if (ln == 63) {
          float unew = 1.f / (s * (1.f / VV) + 1e-16f);
          ast(&upair[orow], ustampP | (u64)__builtin_bit_cast(unsigned, unew));
        }
      }
    }
    // no trailing barrier: next iter's stamp polls are the cross-block fence
  }

  if (converged) {  // restore pre-check state (reference exit semantics)
    __syncthreads();  // quiesce wave0's uf stash before overwrite
    uf[t] = u_prev[t];
    if (t < 128) vf[t] = v_prev[t];
    __syncthreads();
  } else {
    // MAXIT path: drain u_1000 (stamp MAXIT+1) into LDS — wave 0 only
    if (t < 64) {
#pragma unroll 1
      for (int j = 0; j < 8; ++j) {
        u64 pvv;
        do { pvv = ald(&upair[64 * j + t]); } while ((unsigned)(pvv >> 32) != (unsigned)(MAXIT + 1));
        uf[64 * j + t] = __builtin_bit_cast(float, (unsigned)pvv);
      }
    }
    __syncthreads();
  }

  // ---- loss partial: sum u_bar * exp(-20c) * v_bar * c over own stripe ----
  float lacc = 0.f;
  for (int i = 0; i < 16; ++i) {
    int row = rB + 32 * i;
    const float* p = cb + (size_t)row * VV + cB * 8;
    f4 x0 = *(const f4*)p;
    f4 x1 = *(const f4*)(p + 4);
    float um = uf[row];
    float inner = 0.f;
#pragma unroll
    for (int e = 0; e < 4; ++e) inner = fmaf(vf[cB * 8 + e] * __expf(-20.f * x0[e]), x0[e], inner);
#pragma unroll
    for (int e = 0; e < 4; ++e) inner = fmaf(vf[cB * 8 + 4 + e] * __expf(-20.f * x1[e]), x1[e], inner);
    lacc = fmaf(um, inner, lacc);
  }
  lacc = red64(lacc);
  if ((t & 63) == 63) wred[t >> 6] = lacc;
  __syncthreads();
  if (t == 0) {
    float s = 0.f;
#pragma unroll
    for (int w = 0; w < 8; ++w) s += wred[w];
    lossp[b] = s;
  }
}

extern "C" __global__ void prep_kernel(u64* partial, u64* upair, float* errb, float* out) {
  int gid = threadIdx.x + blockIdx.x * 256;
  for (int i = gid; i < NB * TT; i += gridDim.x * 256) partial[i] = 0ull;
  if (gid < TT) upair[gid] = (1ull << 32) | (u64)0x3f800000u;  // stamp 1 = u_0 = 1.0f
  if (gid < NCHK) errb[gid] = 0.f;
  if (gid == 0) out[0] = 0.f;
}

extern "C" __global__ void final_kernel(const float* __restrict__ lossp, float* __restrict__ out) {
  int t = threadIdx.x;  // 64 threads, one wave
  float s = 0.f;
  for (int i = t; i < NB; i += 64) s += lossp[i];
  s = red64(s);
  if (t == 63) out[0] = s * (100.0f / ((float)TT * (float)VV));
}

extern "C" void kernel_launch(void* const* d_in, const int* in_sizes, int n_in,
                              void* d_out, int out_size, void* d_ws, size_t ws_size,
                              hipStream_t stream) {
  const float* cost = (const float*)d_in[0];
  float* out = (float*)d_out;
  char* ws = (char*)d_ws;
  u64*   partial = (u64*)ws;                      // 250*512 u64 = 1,024,000 B (pad to 1 MiB)
  u64*   upair   = (u64*)(ws + 1048576);          // 512 u64 = 4096 B
  float* errb    = (float*)(ws + 1052672);        // 20 f32
  float* lossp   = (float*)(ws + 1052800);        // 250 f32

  prep_kernel<<<512, 256, 0, stream>>>(partial, upair, errb, out);

  (void)hipFuncSetAttribute((const void*)sink_kernel,
                            hipFuncAttributeMaxDynamicSharedMemorySize, LDS_BYTES);
  void* args[] = {(void*)&cost, (void*)&partial, (void*)&upair, (void*)&errb, (void*)&lossp};
  (void)hipLaunchCooperativeKernel((const void*)sink_kernel, dim3(NB), dim3(NTHR),
                                   args, LDS_BYTES, stream);

  final_kernel<<<1, 64, 0, stream>>>(lossp, out);
}

// Round 6
// 592.908 us; speedup vs baseline: 2.8492x; 2.8492x over previous
//
#include <hip/hip_runtime.h>
#include <math.h>

#define TT 512
#define VV 32000
#define NB 250          // blocks; 250*128 = 32000 columns
#define NTHR 512        // 8 waves
#define BCOLS 128
#define MAXIT 1000
#define CHK 50
#define NCHK (MAXIT / CHK)
#define PSTRIDE 256     // partial row stride (250 used, padded)
#define LDS_BYTES 136576

typedef float f4 __attribute__((ext_vector_type(4)));
typedef _Float16 h8 __attribute__((ext_vector_type(8)));
typedef _Float16 h2 __attribute__((ext_vector_type(2)));
typedef unsigned long long u64;

// ---- DPP wave reductions ----
template <int CTRL>
__device__ __forceinline__ float dpp_add(float x) {
  int y = __builtin_amdgcn_update_dpp(0, __builtin_bit_cast(int, x), CTRL, 0xF, 0xF, true);
  return x + __builtin_bit_cast(float, y);
}
__device__ __forceinline__ float red16(float x) {  // valid on lanes 15 mod 16
  x = dpp_add<0x111>(x); x = dpp_add<0x112>(x);
  x = dpp_add<0x114>(x); x = dpp_add<0x118>(x);
  return x;
}
__device__ __forceinline__ float red32(float x) {  // valid on lanes 31, 63
  x = red16(x); x = dpp_add<0x142>(x); return x;
}
__device__ __forceinline__ float red64(float x) {  // valid on lane 63
  x = red32(x); x = dpp_add<0x143>(x); return x;
}

__device__ __forceinline__ int fswz(int row) { return (row ^ (row >> 5)) & 15; }

__device__ __forceinline__ u64 ald(const u64* p) {
  return __hip_atomic_load(p, __ATOMIC_RELAXED, __HIP_MEMORY_SCOPE_AGENT);
}
__device__ __forceinline__ void ast(u64* p, u64 v) {
  __hip_atomic_store(p, v, __ATOMIC_RELAXED, __HIP_MEMORY_SCOPE_AGENT);
}
__device__ __forceinline__ float aldf(const float* p) {
  return __hip_atomic_load(p, __ATOMIC_RELAXED, __HIP_MEMORY_SCOPE_AGENT);
}

extern "C" __global__ void __launch_bounds__(NTHR, 1)
sink_kernel(const float* __restrict__ cost, u64* __restrict__ partial,
            u64* __restrict__ upair, float* __restrict__ errb,
            float* __restrict__ lossp) {
  extern __shared__ char smem[];
  h8*       tile8  = (h8*)smem;                      // 512 x 16 chunks (swizzled), 128 KB
  float*    uf     = (float*)(smem + 131072);        // 512 f32
  float*    u_prev = (float*)(smem + 133120);        // 512 f32
  float*    vf     = (float*)(smem + 135168);        // 128 f32
  float*    v_prev = (float*)(smem + 135680);        // 128 f32
  _Float16* vh     = (_Float16*)(smem + 136192);     // 128 f16
  h8*       vh8    = (h8*)vh;
  float*    errw   = (float*)(smem + 136448);        // 16 f32
  float*    wred   = (float*)(smem + 136512);        // 8 f32
  int*      jflag  = (int*)(smem + 136544);          // 8 i32 (row-group flags)

  const int t  = threadIdx.x;
  const int b  = blockIdx.x;
  const int cB = t & 15;        // chunk (8 cols)   — row-wise map (Phase B)
  const int rB = t >> 4;        // row slice 0..31
  const int gA = t >> 5;        // col-chunk        — Phase A map
  const int sA = t & 31;        // row-within-chunk 0..31
  const int wv = t >> 6, ln = t & 63;

  const float* cb = cost + (size_t)b * BCOLS;

  // ---- load tile: K~ = fp16(exp(-20 c)) ----
  for (int i = 0; i < 16; ++i) {
    int row = rB + 32 * i;
    const float* p = cb + (size_t)row * VV + cB * 8;
    f4 x0 = *(const f4*)p;
    f4 x1 = *(const f4*)(p + 4);
    h8 kk;
#pragma unroll
    for (int e = 0; e < 4; ++e) kk[e]     = (_Float16)__expf(-20.f * x0[e]);
#pragma unroll
    for (int e = 0; e < 4; ++e) kk[4 + e] = (_Float16)__expf(-20.f * x1[e]);
    tile8[row * 16 + (cB ^ fswz(row))] = kk;
  }
  if (t < 8) jflag[t] = 0;
  __syncthreads();

  const int rlo = (b * TT) / NB, rhi = ((b + 1) * TT) / NB;  // owned rows
  const bool writerA = ((t & 31) == 31);
  bool converged = false;

  for (int it = 0; it < MAXIT; ++it) {
    const unsigned stU = (unsigned)(it + 1);   // stamp consumed (u_it) & published (partials)
    const u64 pubstamp = ((u64)(it + 1)) << 32;
    const u64 upub     = ((u64)(it + 2)) << 32; // upair publish stamp (u_{it+1})
    const bool chkc = (it > 0) && (it % CHK == 0);
    const bool pending = ((it % CHK) == 1) && (it > CHK);
    const int ciW = it / CHK - 1;
    const int ciR = (it - 1) / CHK - 1;

    if (pending) { u_prev[t] = uf[t]; __syncthreads(); }

    // ---- Phase A: acc_j = sum_rows K~ * u_bar ----
    float acc[8];
#pragma unroll
    for (int e = 0; e < 8; ++e) acc[e] = 0.f;

    if (t < 64) {
      // wave 0: sole global poller, 8 row-groups in flight, re-issue stale only.
      // All spins whole-wave uniform (__all) — no intra-wave producer/consumer.
      u64 pv[8];
#pragma unroll
      for (int j = 0; j < 8; ++j) pv[j] = ald(&upair[64 * j + t]);
      unsigned pend = 0xFFu;
      while (pend) {
        unsigned prog = 0;
#pragma unroll
        for (int j = 0; j < 8; ++j) {
          if (!(pend & (1u << j))) continue;
          if (__all((unsigned)(pv[j] >> 32) == stU)) {
            uf[64 * j + t] = __builtin_bit_cast(float, (unsigned)pv[j]);
            asm volatile("s_waitcnt lgkmcnt(0)" ::: "memory");
            if (t == 0)
              __hip_atomic_store(&jflag[j], (int)stU, __ATOMIC_RELEASE,
                                 __HIP_MEMORY_SCOPE_WORKGROUP);
            pend &= ~(1u << j);
            prog = 1;
            if (pending && j == 0) {
              unsigned eb = 0;
              if (t == 0) eb = __builtin_bit_cast(unsigned, aldf(&errb[ciR]));
              eb = __builtin_amdgcn_readfirstlane(eb);
              if (__builtin_bit_cast(float, eb) < 0.005f * VV) converged = true;
            }
          } else {
            pv[j] = ald(&upair[64 * j + t]);
          }
        }
        if (converged) break;
        if (pend && !prog) __builtin_amdgcn_s_sleep(1);
      }
      if (!converged) {
#pragma unroll
        for (int i = 0; i < 16; ++i) {
          int row = 32 * i + sA;
          h8 kk = tile8[row * 16 + (gA ^ fswz(row))];
          float uu = uf[row];
#pragma unroll
          for (int e = 0; e < 8; ++e) acc[e] = fmaf((float)kk[e], uu, acc[e]);
        }
      }
    } else {
      // waves 1-7: consume row-groups as wave 0 releases them (cross-wave spin: safe)
#pragma unroll 1
      for (int j = 0; j < 8; ++j) {
        while (__hip_atomic_load(&jflag[j], __ATOMIC_ACQUIRE,
                                 __HIP_MEMORY_SCOPE_WORKGROUP) != (int)stU)
          __builtin_amdgcn_s_sleep(1);
        if (pending && j == 0) {
          unsigned eb = 0;
          if (ln == 0) eb = __builtin_bit_cast(unsigned, aldf(&errb[ciR]));
          eb = __builtin_amdgcn_readfirstlane(eb);
          if (__builtin_bit_cast(float, eb) < 0.005f * VV) { converged = true; break; }
        }
#pragma unroll
        for (int ii = 0; ii < 2; ++ii) {
          int row = 64 * j + 32 * ii + sA;
          h8 kk = tile8[row * 16 + (gA ^ fswz(row))];
          float uu = uf[row];
#pragma unroll
          for (int e = 0; e < 8; ++e) acc[e] = fmaf((float)kk[e], uu, acc[e]);
        }
      }
    }
    if (converged) break;  // uniform: errb stable & identical across blocks

#pragma unroll
    for (int e = 0; e < 8; ++e) acc[e] = red32(acc[e]);

    // ---- v_bar = 1/(Sa + 1e-16); err uses OLD v ----
    if (writerA) {
      float el = 0.f;
#pragma unroll
      for (int e = 0; e < 8; ++e) {
        float sa = acc[e] * (1.f / TT);
        float vo = vf[gA * 8 + e];
        if (chkc) { el += fabsf(vo * sa - 1.f); v_prev[gA * 8 + e] = vo; }
        float nv = 1.f / (sa + 1e-16f);
        vf[gA * 8 + e] = nv;
        vh[gA * 8 + e] = (_Float16)nv;
      }
      if (chkc) errw[gA] = el;
    }
    __syncthreads();
    if (chkc) {
      if (t == 0) {
        float s = 0.f;
#pragma unroll
        for (int w = 0; w < 16; ++w) s += errw[w];
        __hip_atomic_fetch_add(&errb[ciW], s, __ATOMIC_RELAXED, __HIP_MEMORY_SCOPE_AGENT);
      }
      __syncthreads();  // drain err add before any partial store of this iter
    }

    // ---- Phase B: row partials -> stamped transposed publish [row][block] ----
    h8 vv = vh8[cB];
    for (int i = 0; i < 16; ++i) {
      int row = rB + 32 * i;
      h8 kk = tile8[row * 16 + (cB ^ fswz(row))];
      float rs = 0.f;
      rs = __builtin_amdgcn_fdot2(h2{kk[0], kk[1]}, h2{vv[0], vv[1]}, rs, false);
      rs = __builtin_amdgcn_fdot2(h2{kk[2], kk[3]}, h2{vv[2], vv[3]}, rs, false);
      rs = __builtin_amdgcn_fdot2(h2{kk[4], kk[5]}, h2{vv[4], vv[5]}, rs, false);
      rs = __builtin_amdgcn_fdot2(h2{kk[6], kk[7]}, h2{vv[6], vv[7]}, rs, false);
      rs = red16(rs);
      if ((t & 15) == 15)
        ast(&partial[(size_t)row * PSTRIDE + b],
            pubstamp | (u64)__builtin_bit_cast(unsigned, rs));
    }

    // ---- owner reduce AFTER all stores: 250-entry sweep on 32 consecutive lines ----
    if (wv < rhi - rlo) {
      const int orow = rlo + wv;
      const u64* prow = partial + (size_t)orow * PSTRIDE;
      u64 pv[4];
#pragma unroll
      for (int k = 0; k < 4; ++k) {
        int bb = ln + 64 * k;
        pv[k] = (bb < NB) ? ald(&prow[bb]) : pubstamp;  // fabricated entries: value 0
      }
      for (;;) {
        bool done = true;
#pragma unroll
        for (int k = 0; k < 4; ++k) {
          if ((unsigned)(pv[k] >> 32) != stU) {
            done = false;
            pv[k] = ald(&prow[ln + 64 * k]);  // reload stale only (guard: bb<NB stale-able)
          }
        }
        if (__all(done)) break;
        __builtin_amdgcn_s_sleep(1);
      }
      float s = 0.f;
#pragma unroll
      for (int k = 0; k < 4; ++k) s += __builtin_bit_cast(float, (unsigned)pv[k]);
      s = red64(s);
      if (ln == 63) {
        float unew = 1.f / (s * (1.f / VV) + 1e-16f);
        ast(&upair[orow], upub | (u64)__builtin_bit_cast(unsigned, unew));
      }
    }
    // no trailing barrier: next iter's stamp polls are the cross-block fence
  }

  if (converged) {  // restore pre-check state (reference exit semantics)
    __syncthreads();  // quiesce wave0's uf stash before overwrite
    uf[t] = u_prev[t];
    if (t < 128) vf[t] = v_prev[t];
    __syncthreads();
  } else {
    // MAXIT path: drain u_1000 (stamp MAXIT+1) into LDS — wave 0, run-once
    if (t < 64) {
#pragma unroll 1
      for (int j = 0; j < 8; ++j) {
        u64 pvv;
        do { pvv = ald(&upair[64 * j + t]); } while ((unsigned)(pvv >> 32) != (unsigned)(MAXIT + 1));
        uf[64 * j + t] = __builtin_bit_cast(float, (unsigned)pvv);
      }
    }
    __syncthreads();
  }

  // ---- loss partial: sum u_bar * exp(-20c) * v_bar * c over own stripe ----
  float lacc = 0.f;
  for (int i = 0; i < 16; ++i) {
    int row = rB + 32 * i;
    const float* p = cb + (size_t)row * VV + cB * 8;
    f4 x0 = *(const f4*)p;
    f4 x1 = *(const f4*)(p + 4);
    float um = uf[row];
    float inner = 0.f;
#pragma unroll
    for (int e = 0; e < 4; ++e) inner = fmaf(vf[cB * 8 + e] * __expf(-20.f * x0[e]), x0[e], inner);
#pragma unroll
    for (int e = 0; e < 4; ++e) inner = fmaf(vf[cB * 8 + 4 + e] * __expf(-20.f * x1[e]), x1[e], inner);
    lacc = fmaf(um, inner, lacc);
  }
  lacc = red64(lacc);
  if ((t & 63) == 63) wred[t >> 6] = lacc;
  __syncthreads();
  if (t == 0) {
    float s = 0.f;
#pragma unroll
    for (int w = 0; w < 8; ++w) s += wred[w];
    lossp[b] = s;
  }
}

extern "C" __global__ void prep_kernel(u64* partial, u64* upair, float* errb, float* out) {
  int gid = threadIdx.x + blockIdx.x * 256;
  for (int i = gid; i < TT * PSTRIDE; i += gridDim.x * 256) partial[i] = 0ull;
  if (gid < TT) upair[gid] = (1ull << 32) | (u64)0x3f800000u;  // stamp 1 = u_0 = 1.0f
  if (gid < NCHK) errb[gid] = 0.f;
  if (gid == 0) out[0] = 0.f;
}

extern "C" __global__ void final_kernel(const float* __restrict__ lossp, float* __restrict__ out) {
  int t = threadIdx.x;  // 64 threads, one wave
  float s = 0.f;
  for (int i = t; i < NB; i += 64) s += lossp[i];
  s = red64(s);
  if (t == 63) out[0] = s * (100.0f / ((float)TT * (float)VV));
}

extern "C" void kernel_launch(void* const* d_in, const int* in_sizes, int n_in,
                              void* d_out, int out_size, void* d_ws, size_t ws_size,
                              hipStream_t stream) {
  const float* cost = (const float*)d_in[0];
  float* out = (float*)d_out;
  char* ws = (char*)d_ws;
  u64*   partial = (u64*)ws;                      // 512*256 u64 = 1,048,576 B
  u64*   upair   = (u64*)(ws + 1048576);          // 512 u64 = 4096 B
  float* errb    = (float*)(ws + 1052672);        // 20 f32
  float* lossp   = (float*)(ws + 1052800);        // 250 f32

  prep_kernel<<<512, 256, 0, stream>>>(partial, upair, errb, out);

  (void)hipFuncSetAttribute((const void*)sink_kernel,
                            hipFuncAttributeMaxDynamicSharedMemorySize, LDS_BYTES);
  void* args[] = {(void*)&cost, (void*)&partial, (void*)&upair, (void*)&errb, (void*)&lossp};
  (void)hipLaunchCooperativeKernel((const void*)sink_kernel, dim3(NB), dim3(NTHR),
                                   args, LDS_BYTES, stream);

  final_kernel<<<1, 64, 0, stream>>>(lossp, out);
}